// Round 5
// baseline (372.605 us; speedup 1.0000x reference)
//
#include <hip/hip_runtime.h>
#include <stdint.h>

#define NEGV -10000000.0f

typedef __attribute__((ext_vector_type(8))) short short8;
typedef __attribute__((ext_vector_type(4))) float f32x4;

__device__ __forceinline__ ushort f2b(float f) {
    uint32_t x = __float_as_uint(f);
    uint32_t r = x + 0x7FFFu + ((x >> 16) & 1u);
    return (ushort)(r >> 16);
}
__device__ __forceinline__ float b2f(ushort u) {
    union { float f; uint32_t i; } v; v.i = ((uint32_t)u) << 16; return v.f;
}

// ---------------- Kernel 0: per-n prep, outputs in MFMA FRAGMENT ORDER ----------
// Bf[n][kc*4+jt][lane][e] = bf16(Bhat[jt*16+li][kc*32+g*8+e]), lane=(g<<4)|li
// Uf[n][kc2*13+dt][lane][e] = bf16(U[kc2*32+g*8+e][dt*16+li])  (zero for d>=200)
// cW[n][j] = dot(U[j], w_u) + b
// => k13's B-operand loads are lane-contiguous 16B chunks (fully coalesced).
__launch_bounds__(256)
__global__ void k0_prep(const float* __restrict__ Ug, const float* __restrict__ wg,
                        const float* __restrict__ bg,
                        ushort* __restrict__ Bf, ushort* __restrict__ Uf,
                        float* __restrict__ cW) {
    __shared__ __align__(16) float sU[64][204];   // pad: col reads 2-way not 16-way
    __shared__ float sW[600];
    const int tid = threadIdx.x, lane = tid & 63, wid = tid >> 6;
    const int n = blockIdx.x;

    for (int i = tid; i < 600; i += 256) sW[i] = wg[i];
    for (int r = wid; r < 64; r += 4) {
        const float* urow = Ug + (size_t)(n * 64 + r) * 200;
        if (lane < 50) *(float4*)&sU[r][lane * 4] = *(const float4*)(urow + lane * 4);
    }
    __syncthreads();
    const float bval = bg[0];

    // Bhat fragments: 28 chunks x 64 lanes x 8 bf16
    ushort* bfn = Bf + (size_t)n * (28 * 512);
    for (int item = tid; item < 28 * 64; item += 256) {
        int chunk = item >> 6, l2 = item & 63;
        int kc = chunk >> 2, jt = chunk & 3;
        int g2 = l2 >> 4, li2 = l2 & 15;
        int j = jt * 16 + li2;
        int d0 = kc * 32 + g2 * 8;
        short8 v;
        #pragma unroll
        for (int e = 0; e < 8; ++e) {
            int d = d0 + e;
            float bh = 0.f;
            if (d < 200) bh = sU[j][d] * sW[400 + d] + sW[d];
            v[e] = (short)f2b(bh);
        }
        *(short8*)(bfn + (size_t)item * 8) = v;
    }

    // U^T fragments: 26 chunks x 64 lanes x 8 bf16
    ushort* ufn = Uf + (size_t)n * (26 * 512);
    for (int item = tid; item < 26 * 64; item += 256) {
        int chunk = item >> 6, l2 = item & 63;
        int kc2 = chunk / 13, dt = chunk % 13;
        int g2 = l2 >> 4, li2 = l2 & 15;
        int d = dt * 16 + li2;
        int j0 = kc2 * 32 + g2 * 8;
        short8 v;
        #pragma unroll
        for (int e = 0; e < 8; ++e)
            v[e] = (d < 200) ? (short)f2b(sU[j0 + e][d]) : (short)0;
        *(short8*)(ufn + (size_t)item * 8) = v;
    }

    // c[j]
    for (int r = wid; r < 64; r += 4) {
        float part = 0.f;
        for (int d = lane; d < 200; d += 64) part += sU[r][d] * sW[200 + d];
        #pragma unroll
        for (int off = 32; off >= 1; off >>= 1) part += __shfl_xor(part, off);
        if (lane == 0) cW[n * 64 + r] = part + bval;
    }
}

// ---------------- Kernel 13: fused GEMM1 + J-softmax + GEMM2 + G[0:600] ----------
// 1 wave/block, 16 t-rows. All global fragment loads coalesced; H via LDS.
__launch_bounds__(64, 4)
__global__ void k13_fused(const float* __restrict__ Hg,
                          const ushort* __restrict__ Bf,
                          const float* __restrict__ cW,
                          const float* __restrict__ qmg,
                          const ushort* __restrict__ Uf,
                          float* __restrict__ SmaxWs,
                          float* __restrict__ Gout) {
    __shared__ __align__(16) ushort sHb[16][232];  // H tile bf16; stride 232 => 2-way
    __shared__ __align__(16) ushort sP[16][80];    // P tile bf16; 16B-aligned rows
    const int lane = threadIdx.x;
    const int g = lane >> 4, li = lane & 15;
    const int n = blockIdx.y, t0 = blockIdx.x * 16;

    // ---- stage H tile (coalesced float4) -> bf16 LDS ----
    const float* Hbase = Hg + (size_t)(n * 1024 + t0) * 200;
    #pragma unroll
    for (int it = 0; it < 13; ++it) {
        int idx = lane + it * 64;
        if (idx < 800) {
            int row = idx / 50, c4 = (idx - row * 50) * 4;
            float4 h = *(const float4*)(Hbase + (size_t)row * 200 + c4);
            uint2 wv;
            wv.x = ((uint)f2b(h.y) << 16) | (uint)f2b(h.x);
            wv.y = ((uint)f2b(h.w) << 16) | (uint)f2b(h.z);
            *(uint2*)&sHb[row][c4] = wv;
        }
    }
    #pragma unroll
    for (int it = 0; it < 4; ++it) {     // zero-pad cols 200..231
        int id2 = lane + it * 64;
        int row = id2 >> 4, c = id2 & 15;
        *(uint*)&sHb[row][200 + c * 2] = 0u;
    }
    // single wave: DS ordering within wave; compiler inserts lgkmcnt waits

    // ---- GEMM1: A from LDS, B coalesced from fragment-ordered Bf ----
    const ushort* Bn = Bf + (size_t)n * (28 * 512);
    f32x4 acc[4];
    #pragma unroll
    for (int jt = 0; jt < 4; ++jt) acc[jt] = (f32x4){0.f, 0.f, 0.f, 0.f};
    const ushort* aRow = &sHb[li][g * 8];
    #pragma unroll
    for (int kc = 0; kc < 7; ++kc) {
        short8 av = *(const short8*)(aRow + kc * 32);
        #pragma unroll
        for (int jt = 0; jt < 4; ++jt) {
            short8 bv = *(const short8*)(Bn + (size_t)((kc * 4 + jt) * 64 + lane) * 8);
            acc[jt] = __builtin_amdgcn_mfma_f32_16x16x32_bf16(av, bv, acc[jt], 0, 0, 0);
        }
    }

    // ---- J-softmax (identical math to verified kernel) ----
    float cj[4], qm[4];
    #pragma unroll
    for (int jt = 0; jt < 4; ++jt) {
        cj[jt] = cW[n * 64 + jt * 16 + li];
        qm[jt] = qmg[n * 64 + jt * 16 + li];
    }
    #pragma unroll
    for (int reg = 0; reg < 4; ++reg) {
        float x[4], y[4];
        float xm = -1e30f, ym = -1e30f;
        #pragma unroll
        for (int jt = 0; jt < 4; ++jt) {
            float s = acc[jt][reg] + cj[jt];
            x[jt] = s * qm[jt];
            y[jt] = (qm[jt] != 0.f) ? s : NEGV;
            xm = fmaxf(xm, x[jt]); ym = fmaxf(ym, y[jt]);
        }
        #pragma unroll
        for (int off = 1; off <= 8; off <<= 1) {
            xm = fmaxf(xm, __shfl_xor(xm, off));
            ym = fmaxf(ym, __shfl_xor(ym, off));
        }
        float e[4], z = 0.f, zm = 0.f;
        #pragma unroll
        for (int jt = 0; jt < 4; ++jt) {
            e[jt] = __expf(x[jt] - xm);
            z += e[jt]; zm += e[jt] * qm[jt];
        }
        #pragma unroll
        for (int off = 1; off <= 8; off <<= 1) {
            z  += __shfl_xor(z, off);
            zm += __shfl_xor(zm, off);
        }
        float inv = 1.f / (zm + 1e-13f * z);
        int trow = g * 4 + reg;
        #pragma unroll
        for (int jt = 0; jt < 4; ++jt) sP[trow][jt * 16 + li] = f2b(e[jt] * qm[jt] * inv);
        if (li == 0) SmaxWs[n * 1024 + t0 + trow] = ym;
    }

    // ---- GEMM2: A from sP, B coalesced from fragment-ordered Uf ----
    const ushort* Un = Uf + (size_t)n * (26 * 512);
    f32x4 acc2[13];
    #pragma unroll
    for (int dt = 0; dt < 13; ++dt) acc2[dt] = (f32x4){0.f, 0.f, 0.f, 0.f};
    #pragma unroll
    for (int kc2 = 0; kc2 < 2; ++kc2) {
        short8 a2 = *(const short8*)(&sP[li][kc2 * 32 + g * 8]);
        #pragma unroll
        for (int dt = 0; dt < 13; ++dt) {
            short8 bv = *(const short8*)(Un + (size_t)((kc2 * 13 + dt) * 64 + lane) * 8);
            acc2[dt] = __builtin_amdgcn_mfma_f32_16x16x32_bf16(a2, bv, acc2[dt], 0, 0, 0);
        }
    }

    // ---- epilogue: G[:,0:600] direct from C-layout (u exact f32; h bf16 as R0) ----
    #pragma unroll
    for (int dt = 0; dt < 13; ++dt) {
        int d = dt * 16 + li;
        if (d < 200) {
            #pragma unroll
            for (int reg = 0; reg < 4; ++reg) {
                int r = g * 4 + reg;
                float h = b2f(sHb[r][d]);
                float u = acc2[dt][reg];
                float* orow = Gout + (size_t)(n * 1024 + t0 + r) * 800;
                __builtin_nontemporal_store(h,     orow + d);
                __builtin_nontemporal_store(u,     orow + 200 + d);
                __builtin_nontemporal_store(h * u, orow + 400 + d);
            }
        }
    }
}

// ---------------- Kernel 2a: T-softmax stats -> a; zero Hbar ---------------------
__launch_bounds__(256)
__global__ void k2a_softmaxT(const float* __restrict__ cmg,
                             const float* __restrict__ SmaxWs,
                             float* __restrict__ aWs,
                             float* __restrict__ HbarWs) {
    __shared__ float red[8];
    const int tid = threadIdx.x, lane = tid & 63, wid = tid >> 6;
    const int n = blockIdx.x;

    float x[4], m[4];
    #pragma unroll
    for (int i = 0; i < 4; ++i) {
        int t = tid + 256 * i;
        float v = SmaxWs[n * 1024 + t];
        m[i] = cmg[(size_t)n * 1024 + t];
        x[i] = v * m[i];
    }
    float mx = fmaxf(fmaxf(x[0], x[1]), fmaxf(x[2], x[3]));
    #pragma unroll
    for (int off = 32; off >= 1; off >>= 1) mx = fmaxf(mx, __shfl_xor(mx, off));
    if (lane == 0) red[wid] = mx;
    __syncthreads();
    float M = fmaxf(fmaxf(red[0], red[1]), fmaxf(red[2], red[3]));
    __syncthreads();
    float e[4], z = 0.f, zm = 0.f;
    #pragma unroll
    for (int i = 0; i < 4; ++i) {
        e[i] = __expf(x[i] - M);
        z += e[i]; zm += e[i] * m[i];
    }
    #pragma unroll
    for (int off = 32; off >= 1; off >>= 1) {
        z  += __shfl_xor(z, off);
        zm += __shfl_xor(zm, off);
    }
    if (lane == 0) { red[wid] = z; red[4 + wid] = zm; }
    __syncthreads();
    float Z  = red[0] + red[1] + red[2] + red[3];
    float Zm = red[4] + red[5] + red[6] + red[7];
    float inv = 1.f / (Zm + 1e-13f * Z);
    #pragma unroll
    for (int i = 0; i < 4; ++i) aWs[n * 1024 + tid + 256 * i] = e[i] * m[i] * inv;
    if (tid < 200) HbarWs[n * 200 + tid] = 0.f;
}

// ---------------- Kernel 2b: Hbar += a-chunk @ H-chunk ---------------------------
__launch_bounds__(256)
__global__ void k2b_hbar(const float* __restrict__ Hg,
                         const float* __restrict__ aWs,
                         float* __restrict__ HbarWs) {
    __shared__ float sA[64];
    const int tid = threadIdx.x;
    const int n = blockIdx.y, t0 = blockIdx.x * 64;
    if (tid < 64) sA[tid] = aWs[n * 1024 + t0 + tid];
    __syncthreads();
    if (tid < 200) {
        const float* hp = Hg + (size_t)(n * 1024 + t0) * 200 + tid;
        float acc = 0.f;
        #pragma unroll 8
        for (int t = 0; t < 64; ++t) acc += sA[t] * hp[(size_t)t * 200];
        atomicAdd(HbarWs + n * 200 + tid, acc);
    }
}

// ---------------- Kernel 4: G[:, 600:800] = H * Hbar -----------------------------
__launch_bounds__(256)
__global__ void k4_hh(const float* __restrict__ Hg,
                      const float* __restrict__ HbarWs,
                      float* __restrict__ Gout) {
    __shared__ __align__(16) float sHb[200];
    const int tid = threadIdx.x, lane = tid & 63, wid = tid >> 6;
    const int n = blockIdx.y, t0 = blockIdx.x * 64;
    if (tid < 200) sHb[tid] = HbarWs[n * 200 + tid];
    __syncthreads();
    for (int r = wid; r < 64; r += 4) {
        if (lane < 50) {
            int d0 = lane * 4;
            const float* hrow = Hg + (size_t)(n * 1024 + t0 + r) * 200;
            float* orow = Gout + (size_t)(n * 1024 + t0 + r) * 800;
            f32x4 h  = *(const f32x4*)(hrow + d0);
            f32x4 hb = *(const f32x4*)&sHb[d0];
            f32x4 hh = h * hb;
            __builtin_nontemporal_store(hh, (f32x4*)(orow + 600 + d0));
        }
    }
}

extern "C" void kernel_launch(void* const* d_in, const int* in_sizes, int n_in,
                              void* d_out, int out_size, void* d_ws, size_t ws_size,
                              hipStream_t stream) {
    (void)in_sizes; (void)n_in; (void)out_size; (void)ws_size;
    const float* Hg  = (const float*)d_in[0];
    const float* Ug  = (const float*)d_in[1];
    const float* cmg = (const float*)d_in[2];
    const float* qmg = (const float*)d_in[3];
    const float* wg  = (const float*)d_in[4];
    const float* bg  = (const float*)d_in[5];
    float* Gout = (float*)d_out;

    char* ws = (char*)d_ws;
    float*  SmaxWs = (float*) (ws);                    // 64*1024*4   =   262,144
    float*  aWs    = (float*) (ws + 262144);           // 64*1024*4   =   262,144
    float*  HbarWs = (float*) (ws + 524288);           // 64*200*4    =    51,200
    float*  cWs    = (float*) (ws + 575488);           // 64*64*4     =    16,384
    ushort* BfWs   = (ushort*)(ws + 591872);           // 64*28*512*2 = 1,835,008
    ushort* UfWs   = (ushort*)(ws + 2426880);          // 64*26*512*2 = 1,703,936
                                                       // total       = 4,130,816

    dim3 blk256(256, 1, 1);
    k0_prep<<<dim3(64, 1, 1), blk256, 0, stream>>>(Ug, wg, bg, BfWs, UfWs, cWs);
    k13_fused<<<dim3(64, 64, 1), dim3(64, 1, 1), 0, stream>>>(Hg, BfWs, cWs, qmg,
                                                              UfWs, SmaxWs, Gout);
    k2a_softmaxT<<<dim3(64, 1, 1), blk256, 0, stream>>>(cmg, SmaxWs, aWs, HbarWs);
    k2b_hbar<<<dim3(16, 64, 1), blk256, 0, stream>>>(Hg, aWs, HbarWs);
    k4_hh<<<dim3(16, 64, 1), blk256, 0, stream>>>(Hg, HbarWs, Gout);
}

// Round 6
// 324.460 us; speedup vs baseline: 1.1484x; 1.1484x over previous
//
#include <hip/hip_runtime.h>
#include <stdint.h>

#define NEGV -10000000.0f

typedef __attribute__((ext_vector_type(8))) short short8;
typedef __attribute__((ext_vector_type(4))) float f32x4;

__device__ __forceinline__ ushort f2b(float f) {
    uint32_t x = __float_as_uint(f);
    uint32_t r = x + 0x7FFFu + ((x >> 16) & 1u);
    return (ushort)(r >> 16);
}
__device__ __forceinline__ float b2f(ushort u) {
    union { float f; uint32_t i; } v; v.i = ((uint32_t)u) << 16; return v.f;
}

// ---------------- Kernel 0: per-n prep, outputs in MFMA FRAGMENT ORDER ----------
// Bf[n][kc*4+jt][lane][e] = bf16(Bhat[jt*16+li][kc*32+g*8+e]), lane=(g<<4)|li
// Uf[n][kc2*13+dt][lane][e] = bf16(U[kc2*32+g*8+e][dt*16+li])  (zero for d>=200)
// cW[n][j] = dot(U[j], w_u) + b
__launch_bounds__(256)
__global__ void k0_prep(const float* __restrict__ Ug, const float* __restrict__ wg,
                        const float* __restrict__ bg,
                        ushort* __restrict__ Bf, ushort* __restrict__ Uf,
                        float* __restrict__ cW) {
    __shared__ __align__(16) float sU[64][204];
    __shared__ float sW[600];
    const int tid = threadIdx.x, lane = tid & 63, wid = tid >> 6;
    const int n = blockIdx.x;

    for (int i = tid; i < 600; i += 256) sW[i] = wg[i];
    for (int r = wid; r < 64; r += 4) {
        const float* urow = Ug + (size_t)(n * 64 + r) * 200;
        if (lane < 50) *(float4*)&sU[r][lane * 4] = *(const float4*)(urow + lane * 4);
    }
    __syncthreads();
    const float bval = bg[0];

    // Bhat fragments: 28 chunks x 64 lanes x 8 bf16
    ushort* bfn = Bf + (size_t)n * (28 * 512);
    for (int item = tid; item < 28 * 64; item += 256) {
        int chunk = item >> 6, l2 = item & 63;
        int kc = chunk >> 2, jt = chunk & 3;
        int g2 = l2 >> 4, li2 = l2 & 15;
        int j = jt * 16 + li2;
        int d0 = kc * 32 + g2 * 8;
        short8 v;
        #pragma unroll
        for (int e = 0; e < 8; ++e) {
            int d = d0 + e;
            float bh = 0.f;
            if (d < 200) bh = sU[j][d] * sW[400 + d] + sW[d];
            v[e] = (short)f2b(bh);
        }
        *(short8*)(bfn + (size_t)item * 8) = v;
    }

    // U^T fragments: 26 chunks x 64 lanes x 8 bf16
    ushort* ufn = Uf + (size_t)n * (26 * 512);
    for (int item = tid; item < 26 * 64; item += 256) {
        int chunk = item >> 6, l2 = item & 63;
        int kc2 = chunk / 13, dt = chunk % 13;
        int g2 = l2 >> 4, li2 = l2 & 15;
        int d = dt * 16 + li2;
        int j0 = kc2 * 32 + g2 * 8;
        short8 v;
        #pragma unroll
        for (int e = 0; e < 8; ++e)
            v[e] = (d < 200) ? (short)f2b(sU[j0 + e][d]) : (short)0;
        *(short8*)(ufn + (size_t)item * 8) = v;
    }

    // c[j]
    for (int r = wid; r < 64; r += 4) {
        float part = 0.f;
        for (int d = lane; d < 200; d += 64) part += sU[r][d] * sW[200 + d];
        #pragma unroll
        for (int off = 32; off >= 1; off >>= 1) part += __shfl_xor(part, off);
        if (lane == 0) cW[n * 64 + r] = part + bval;
    }
}

// ---------------- Kernel 13: fused GEMM1 + J-softmax + GEMM2 + G[200:600] --------
// 1 wave/block, 16 t-rows. Coalesced fragment loads; vectorized 800B-segment stores.
__launch_bounds__(64, 4)
__global__ void k13_fused(const float* __restrict__ Hg,
                          const ushort* __restrict__ Bf,
                          const float* __restrict__ cW,
                          const float* __restrict__ qmg,
                          const ushort* __restrict__ Uf,
                          float* __restrict__ SmaxWs,
                          float* __restrict__ Gout) {
    __shared__ __align__(16) ushort sHb[16][232];  // H tile bf16 (MFMA A + hu product)
    __shared__ __align__(16) ushort sP[16][80];    // P tile bf16
    __shared__ __align__(16) ushort sU2[16][208];  // U_ tile bf16 (epilogue transpose)
    const int lane = threadIdx.x;
    const int g = lane >> 4, li = lane & 15;
    const int n = blockIdx.y, t0 = blockIdx.x * 16;

    // ---- stage H tile (coalesced float4) -> bf16 LDS ----
    const float* Hbase = Hg + (size_t)(n * 1024 + t0) * 200;
    #pragma unroll
    for (int it = 0; it < 13; ++it) {
        int idx = lane + it * 64;
        if (idx < 800) {
            int row = idx / 50, c4 = (idx - row * 50) * 4;
            float4 h = *(const float4*)(Hbase + (size_t)row * 200 + c4);
            uint2 wv;
            wv.x = ((uint)f2b(h.y) << 16) | (uint)f2b(h.x);
            wv.y = ((uint)f2b(h.w) << 16) | (uint)f2b(h.z);
            *(uint2*)&sHb[row][c4] = wv;
        }
    }
    #pragma unroll
    for (int it = 0; it < 4; ++it) {     // zero-pad cols 200..231
        int id2 = lane + it * 64;
        int row = id2 >> 4, c = id2 & 15;
        *(uint*)&sHb[row][200 + c * 2] = 0u;
    }

    // ---- GEMM1: A from LDS, B coalesced from fragment-ordered Bf ----
    const ushort* Bn = Bf + (size_t)n * (28 * 512);
    f32x4 acc[4];
    #pragma unroll
    for (int jt = 0; jt < 4; ++jt) acc[jt] = (f32x4){0.f, 0.f, 0.f, 0.f};
    const ushort* aRow = &sHb[li][g * 8];
    #pragma unroll
    for (int kc = 0; kc < 7; ++kc) {
        short8 av = *(const short8*)(aRow + kc * 32);
        #pragma unroll
        for (int jt = 0; jt < 4; ++jt) {
            short8 bv = *(const short8*)(Bn + (size_t)((kc * 4 + jt) * 64 + lane) * 8);
            acc[jt] = __builtin_amdgcn_mfma_f32_16x16x32_bf16(av, bv, acc[jt], 0, 0, 0);
        }
    }

    // ---- J-softmax (identical math to verified kernel) ----
    float cj[4], qm[4];
    #pragma unroll
    for (int jt = 0; jt < 4; ++jt) {
        cj[jt] = cW[n * 64 + jt * 16 + li];
        qm[jt] = qmg[n * 64 + jt * 16 + li];
    }
    #pragma unroll
    for (int reg = 0; reg < 4; ++reg) {
        float x[4], y[4];
        float xm = -1e30f, ym = -1e30f;
        #pragma unroll
        for (int jt = 0; jt < 4; ++jt) {
            float s = acc[jt][reg] + cj[jt];
            x[jt] = s * qm[jt];
            y[jt] = (qm[jt] != 0.f) ? s : NEGV;
            xm = fmaxf(xm, x[jt]); ym = fmaxf(ym, y[jt]);
        }
        #pragma unroll
        for (int off = 1; off <= 8; off <<= 1) {
            xm = fmaxf(xm, __shfl_xor(xm, off));
            ym = fmaxf(ym, __shfl_xor(ym, off));
        }
        float e[4], z = 0.f, zm = 0.f;
        #pragma unroll
        for (int jt = 0; jt < 4; ++jt) {
            e[jt] = __expf(x[jt] - xm);
            z += e[jt]; zm += e[jt] * qm[jt];
        }
        #pragma unroll
        for (int off = 1; off <= 8; off <<= 1) {
            z  += __shfl_xor(z, off);
            zm += __shfl_xor(zm, off);
        }
        float inv = 1.f / (zm + 1e-13f * z);
        int trow = g * 4 + reg;
        #pragma unroll
        for (int jt = 0; jt < 4; ++jt) sP[trow][jt * 16 + li] = f2b(e[jt] * qm[jt] * inv);
        if (li == 0) SmaxWs[n * 1024 + t0 + trow] = ym;
    }

    // ---- GEMM2: A from sP, B coalesced from fragment-ordered Uf ----
    const ushort* Un = Uf + (size_t)n * (26 * 512);
    f32x4 acc2[13];
    #pragma unroll
    for (int dt = 0; dt < 13; ++dt) acc2[dt] = (f32x4){0.f, 0.f, 0.f, 0.f};
    #pragma unroll
    for (int kc2 = 0; kc2 < 2; ++kc2) {
        short8 a2 = *(const short8*)(&sP[li][kc2 * 32 + g * 8]);
        #pragma unroll
        for (int dt = 0; dt < 13; ++dt) {
            short8 bv = *(const short8*)(Un + (size_t)((kc2 * 13 + dt) * 64 + lane) * 8);
            acc2[dt] = __builtin_amdgcn_mfma_f32_16x16x32_bf16(a2, bv, acc2[dt], 0, 0, 0);
        }
    }

    // ---- stage U_ (bf16) into LDS: transpose C-layout -> row-major ----
    #pragma unroll
    for (int dt = 0; dt < 13; ++dt) {
        int d = dt * 16 + li;
        if (d < 200) {
            #pragma unroll
            for (int reg = 0; reg < 4; ++reg)
                sU2[g * 4 + reg][d] = f2b(acc2[dt][reg]);
        }
    }

    // ---- epilogue: G[:,200:600] = [U_ | H*U_], coalesced 800B segments ----
    for (int r = 0; r < 16; ++r) {
        if (lane < 50) {
            int d0 = lane * 4;
            float* orow = Gout + (size_t)(n * 1024 + t0 + r) * 800;
            uint2 uraw = *(const uint2*)&sU2[r][d0];
            uint2 hraw = *(const uint2*)&sHb[r][d0];
            f32x4 u, h;
            u[0] = b2f((ushort)(uraw.x & 0xffffu)); u[1] = b2f((ushort)(uraw.x >> 16));
            u[2] = b2f((ushort)(uraw.y & 0xffffu)); u[3] = b2f((ushort)(uraw.y >> 16));
            h[0] = b2f((ushort)(hraw.x & 0xffffu)); h[1] = b2f((ushort)(hraw.x >> 16));
            h[2] = b2f((ushort)(hraw.y & 0xffffu)); h[3] = b2f((ushort)(hraw.y >> 16));
            f32x4 hu = h * u;
            __builtin_nontemporal_store(u,  (f32x4*)(orow + 200 + d0));
            __builtin_nontemporal_store(hu, (f32x4*)(orow + 400 + d0));
        }
    }
}

// ---------------- Kernel 2a: T-softmax stats -> a; zero Hbar ---------------------
__launch_bounds__(256)
__global__ void k2a_softmaxT(const float* __restrict__ cmg,
                             const float* __restrict__ SmaxWs,
                             float* __restrict__ aWs,
                             float* __restrict__ HbarWs) {
    __shared__ float red[8];
    const int tid = threadIdx.x, lane = tid & 63, wid = tid >> 6;
    const int n = blockIdx.x;

    float x[4], m[4];
    #pragma unroll
    for (int i = 0; i < 4; ++i) {
        int t = tid + 256 * i;
        float v = SmaxWs[n * 1024 + t];
        m[i] = cmg[(size_t)n * 1024 + t];
        x[i] = v * m[i];
    }
    float mx = fmaxf(fmaxf(x[0], x[1]), fmaxf(x[2], x[3]));
    #pragma unroll
    for (int off = 32; off >= 1; off >>= 1) mx = fmaxf(mx, __shfl_xor(mx, off));
    if (lane == 0) red[wid] = mx;
    __syncthreads();
    float M = fmaxf(fmaxf(red[0], red[1]), fmaxf(red[2], red[3]));
    __syncthreads();
    float e[4], z = 0.f, zm = 0.f;
    #pragma unroll
    for (int i = 0; i < 4; ++i) {
        e[i] = __expf(x[i] - M);
        z += e[i]; zm += e[i] * m[i];
    }
    #pragma unroll
    for (int off = 32; off >= 1; off >>= 1) {
        z  += __shfl_xor(z, off);
        zm += __shfl_xor(zm, off);
    }
    if (lane == 0) { red[wid] = z; red[4 + wid] = zm; }
    __syncthreads();
    float Z  = red[0] + red[1] + red[2] + red[3];
    float Zm = red[4] + red[5] + red[6] + red[7];
    float inv = 1.f / (Zm + 1e-13f * Z);
    #pragma unroll
    for (int i = 0; i < 4; ++i) aWs[n * 1024 + tid + 256 * i] = e[i] * m[i] * inv;
    if (tid < 200) HbarWs[n * 200 + tid] = 0.f;
}

// ---------------- Kernel 2b: Hbar += a-chunk @ H-chunk ---------------------------
__launch_bounds__(256)
__global__ void k2b_hbar(const float* __restrict__ Hg,
                         const float* __restrict__ aWs,
                         float* __restrict__ HbarWs) {
    __shared__ float sA[64];
    const int tid = threadIdx.x;
    const int n = blockIdx.y, t0 = blockIdx.x * 64;
    if (tid < 64) sA[tid] = aWs[n * 1024 + t0 + tid];
    __syncthreads();
    if (tid < 200) {
        const float* hp = Hg + (size_t)(n * 1024 + t0) * 200 + tid;
        float acc = 0.f;
        #pragma unroll 8
        for (int t = 0; t < 64; ++t) acc += sA[t] * hp[(size_t)t * 200];
        atomicAdd(HbarWs + n * 200 + tid, acc);
    }
}

// ---------------- Kernel 4: G[:,0:200] = H (exact); G[:,600:800] = H * Hbar ------
__launch_bounds__(256)
__global__ void k4_hh(const float* __restrict__ Hg,
                      const float* __restrict__ HbarWs,
                      float* __restrict__ Gout) {
    __shared__ __align__(16) float sHb[200];
    const int tid = threadIdx.x, lane = tid & 63, wid = tid >> 6;
    const int n = blockIdx.y, t0 = blockIdx.x * 64;
    if (tid < 200) sHb[tid] = HbarWs[n * 200 + tid];
    __syncthreads();
    for (int r = wid; r < 64; r += 4) {
        if (lane < 50) {
            int d0 = lane * 4;
            const float* hrow = Hg + (size_t)(n * 1024 + t0 + r) * 200;
            float* orow = Gout + (size_t)(n * 1024 + t0 + r) * 800;
            f32x4 h  = *(const f32x4*)(hrow + d0);
            f32x4 hb = *(const f32x4*)&sHb[d0];
            f32x4 hh = h * hb;
            __builtin_nontemporal_store(h,  (f32x4*)(orow + d0));
            __builtin_nontemporal_store(hh, (f32x4*)(orow + 600 + d0));
        }
    }
}

extern "C" void kernel_launch(void* const* d_in, const int* in_sizes, int n_in,
                              void* d_out, int out_size, void* d_ws, size_t ws_size,
                              hipStream_t stream) {
    (void)in_sizes; (void)n_in; (void)out_size; (void)ws_size;
    const float* Hg  = (const float*)d_in[0];
    const float* Ug  = (const float*)d_in[1];
    const float* cmg = (const float*)d_in[2];
    const float* qmg = (const float*)d_in[3];
    const float* wg  = (const float*)d_in[4];
    const float* bg  = (const float*)d_in[5];
    float* Gout = (float*)d_out;

    char* ws = (char*)d_ws;
    float*  SmaxWs = (float*) (ws);                    // 64*1024*4   =   262,144
    float*  aWs    = (float*) (ws + 262144);           // 64*1024*4   =   262,144
    float*  HbarWs = (float*) (ws + 524288);           // 64*200*4    =    51,200
    float*  cWs    = (float*) (ws + 575488);           // 64*64*4     =    16,384
    ushort* BfWs   = (ushort*)(ws + 591872);           // 64*28*512*2 = 1,835,008
    ushort* UfWs   = (ushort*)(ws + 2426880);          // 64*26*512*2 = 1,703,936
                                                       // total       = 4,130,816

    dim3 blk256(256, 1, 1);
    k0_prep<<<dim3(64, 1, 1), blk256, 0, stream>>>(Ug, wg, bg, BfWs, UfWs, cWs);
    k13_fused<<<dim3(64, 64, 1), dim3(64, 1, 1), 0, stream>>>(Hg, BfWs, cWs, qmg,
                                                              UfWs, SmaxWs, Gout);
    k2a_softmaxT<<<dim3(64, 1, 1), blk256, 0, stream>>>(cmg, SmaxWs, aWs, HbarWs);
    k2b_hbar<<<dim3(16, 64, 1), blk256, 0, stream>>>(Hg, aWs, HbarWs);
    k4_hh<<<dim3(16, 64, 1), blk256, 0, stream>>>(Hg, HbarWs, Gout);
}

// Round 7
// 318.536 us; speedup vs baseline: 1.1697x; 1.0186x over previous
//
#include <hip/hip_runtime.h>
#include <stdint.h>

#define NEGV -10000000.0f

typedef __attribute__((ext_vector_type(8))) short short8;
typedef __attribute__((ext_vector_type(4))) float f32x4;

__device__ __forceinline__ ushort f2b(float f) {
    uint32_t x = __float_as_uint(f);
    uint32_t r = x + 0x7FFFu + ((x >> 16) & 1u);
    return (ushort)(r >> 16);
}
__device__ __forceinline__ float b2f(ushort u) {
    union { float f; uint32_t i; } v; v.i = ((uint32_t)u) << 16; return v.f;
}

// ---------------- Kernel 0: per-n prep, outputs in MFMA FRAGMENT ORDER ----------
// Bf[n][kc*4+jt][lane][e] = bf16(Bhat[jt*16+li][kc*32+g*8+e]), lane=(g<<4)|li
// Uf[n][kc2*13+dt][lane][e] = bf16(U[kc2*32+g*8+e][dt*16+li])  (zero for d>=200)
// cW[n][j] = dot(U[j], w_u) + b
__launch_bounds__(256)
__global__ void k0_prep(const float* __restrict__ Ug, const float* __restrict__ wg,
                        const float* __restrict__ bg,
                        ushort* __restrict__ Bf, ushort* __restrict__ Uf,
                        float* __restrict__ cW) {
    __shared__ __align__(16) float sU[64][204];
    __shared__ float sW[600];
    const int tid = threadIdx.x, lane = tid & 63, wid = tid >> 6;
    const int n = blockIdx.x;

    for (int i = tid; i < 600; i += 256) sW[i] = wg[i];
    for (int r = wid; r < 64; r += 4) {
        const float* urow = Ug + (size_t)(n * 64 + r) * 200;
        if (lane < 50) *(float4*)&sU[r][lane * 4] = *(const float4*)(urow + lane * 4);
    }
    __syncthreads();
    const float bval = bg[0];

    // Bhat fragments: 28 chunks x 64 lanes x 8 bf16
    ushort* bfn = Bf + (size_t)n * (28 * 512);
    for (int item = tid; item < 28 * 64; item += 256) {
        int chunk = item >> 6, l2 = item & 63;
        int kc = chunk >> 2, jt = chunk & 3;
        int g2 = l2 >> 4, li2 = l2 & 15;
        int j = jt * 16 + li2;
        int d0 = kc * 32 + g2 * 8;
        short8 v;
        #pragma unroll
        for (int e = 0; e < 8; ++e) {
            int d = d0 + e;
            float bh = 0.f;
            if (d < 200) bh = sU[j][d] * sW[400 + d] + sW[d];
            v[e] = (short)f2b(bh);
        }
        *(short8*)(bfn + (size_t)item * 8) = v;
    }

    // U^T fragments: 26 chunks x 64 lanes x 8 bf16
    ushort* ufn = Uf + (size_t)n * (26 * 512);
    for (int item = tid; item < 26 * 64; item += 256) {
        int chunk = item >> 6, l2 = item & 63;
        int kc2 = chunk / 13, dt = chunk % 13;
        int g2 = l2 >> 4, li2 = l2 & 15;
        int d = dt * 16 + li2;
        int j0 = kc2 * 32 + g2 * 8;
        short8 v;
        #pragma unroll
        for (int e = 0; e < 8; ++e)
            v[e] = (d < 200) ? (short)f2b(sU[j0 + e][d]) : (short)0;
        *(short8*)(ufn + (size_t)item * 8) = v;
    }

    // c[j]
    for (int r = wid; r < 64; r += 4) {
        float part = 0.f;
        for (int d = lane; d < 200; d += 64) part += sU[r][d] * sW[200 + d];
        #pragma unroll
        for (int off = 32; off >= 1; off >>= 1) part += __shfl_xor(part, off);
        if (lane == 0) cW[n * 64 + r] = part + bval;
    }
}

// ---------------- Kernel 13: fused GEMM1 + J-softmax + GEMM2 + G[200:600] --------
// 1 wave/block, 16 t-rows. LDS 9.75KB (U_ overlays H tile) -> ~16 blocks/CU.
__launch_bounds__(64, 4)
__global__ void k13_fused(const float* __restrict__ Hg,
                          const ushort* __restrict__ Bf,
                          const float* __restrict__ cW,
                          const float* __restrict__ qmg,
                          const ushort* __restrict__ Uf,
                          float* __restrict__ SmaxWs,
                          float* __restrict__ Gout) {
    // sMem: first holds H tile bf16 [16][232] (MFMA A operand);
    // after GEMM1 finishes reading it, U_ bf16 [16][232-stride] overlays it.
    __shared__ __align__(16) ushort sMem[16 * 232];   // 7424 B
    __shared__ __align__(16) ushort sP[16][80];       // 2560 B  -> total 9984 B
    const int lane = threadIdx.x;
    const int g = lane >> 4, li = lane & 15;
    const int n = blockIdx.y, t0 = blockIdx.x * 16;

    // ---- stage H tile (coalesced float4) -> bf16 LDS ----
    const float* Hbase = Hg + (size_t)(n * 1024 + t0) * 200;
    #pragma unroll
    for (int it = 0; it < 13; ++it) {
        int idx = lane + it * 64;
        if (idx < 800) {
            int row = idx / 50, c4 = (idx - row * 50) * 4;
            float4 h = *(const float4*)(Hbase + (size_t)row * 200 + c4);
            uint2 wv;
            wv.x = ((uint)f2b(h.y) << 16) | (uint)f2b(h.x);
            wv.y = ((uint)f2b(h.w) << 16) | (uint)f2b(h.z);
            *(uint2*)&sMem[row * 232 + c4] = wv;
        }
    }
    #pragma unroll
    for (int it = 0; it < 4; ++it) {     // zero-pad cols 200..231
        int id2 = lane + it * 64;
        int row = id2 >> 4, c = id2 & 15;
        *(uint*)&sMem[row * 232 + 200 + c * 2] = 0u;
    }

    // ---- GEMM1: A from LDS, B coalesced from fragment-ordered Bf ----
    const ushort* Bn = Bf + (size_t)n * (28 * 512);
    f32x4 acc[4];
    #pragma unroll
    for (int jt = 0; jt < 4; ++jt) acc[jt] = (f32x4){0.f, 0.f, 0.f, 0.f};
    const ushort* aRow = &sMem[li * 232 + g * 8];
    #pragma unroll
    for (int kc = 0; kc < 7; ++kc) {
        short8 av = *(const short8*)(aRow + kc * 32);
        #pragma unroll
        for (int jt = 0; jt < 4; ++jt) {
            short8 bv = *(const short8*)(Bn + (size_t)((kc * 4 + jt) * 64 + lane) * 8);
            acc[jt] = __builtin_amdgcn_mfma_f32_16x16x32_bf16(av, bv, acc[jt], 0, 0, 0);
        }
    }

    // ---- J-softmax (identical math to verified kernel) ----
    float cj[4], qm[4];
    #pragma unroll
    for (int jt = 0; jt < 4; ++jt) {
        cj[jt] = cW[n * 64 + jt * 16 + li];
        qm[jt] = qmg[n * 64 + jt * 16 + li];
    }
    #pragma unroll
    for (int reg = 0; reg < 4; ++reg) {
        float x[4], y[4];
        float xm = -1e30f, ym = -1e30f;
        #pragma unroll
        for (int jt = 0; jt < 4; ++jt) {
            float s = acc[jt][reg] + cj[jt];
            x[jt] = s * qm[jt];
            y[jt] = (qm[jt] != 0.f) ? s : NEGV;
            xm = fmaxf(xm, x[jt]); ym = fmaxf(ym, y[jt]);
        }
        #pragma unroll
        for (int off = 1; off <= 8; off <<= 1) {
            xm = fmaxf(xm, __shfl_xor(xm, off));
            ym = fmaxf(ym, __shfl_xor(ym, off));
        }
        float e[4], z = 0.f, zm = 0.f;
        #pragma unroll
        for (int jt = 0; jt < 4; ++jt) {
            e[jt] = __expf(x[jt] - xm);
            z += e[jt]; zm += e[jt] * qm[jt];
        }
        #pragma unroll
        for (int off = 1; off <= 8; off <<= 1) {
            z  += __shfl_xor(z, off);
            zm += __shfl_xor(zm, off);
        }
        float inv = 1.f / (zm + 1e-13f * z);
        int trow = g * 4 + reg;
        #pragma unroll
        for (int jt = 0; jt < 4; ++jt) sP[trow][jt * 16 + li] = f2b(e[jt] * qm[jt] * inv);
        if (li == 0) SmaxWs[n * 1024 + t0 + trow] = ym;
    }

    // ---- GEMM2: A from sP, B coalesced from fragment-ordered Uf ----
    const ushort* Un = Uf + (size_t)n * (26 * 512);
    f32x4 acc2[13];
    #pragma unroll
    for (int dt = 0; dt < 13; ++dt) acc2[dt] = (f32x4){0.f, 0.f, 0.f, 0.f};
    #pragma unroll
    for (int kc2 = 0; kc2 < 2; ++kc2) {
        short8 a2 = *(const short8*)(&sP[li][kc2 * 32 + g * 8]);
        #pragma unroll
        for (int dt = 0; dt < 13; ++dt) {
            short8 bv = *(const short8*)(Un + (size_t)((kc2 * 13 + dt) * 64 + lane) * 8);
            acc2[dt] = __builtin_amdgcn_mfma_f32_16x16x32_bf16(a2, bv, acc2[dt], 0, 0, 0);
        }
    }

    // ---- overlay U_ (bf16) onto sMem (H tile fully consumed by GEMM1) ----
    asm volatile("s_waitcnt lgkmcnt(0)" ::: "memory");
    #pragma unroll
    for (int dt = 0; dt < 13; ++dt) {
        int d = dt * 16 + li;
        if (d < 200) {
            #pragma unroll
            for (int reg = 0; reg < 4; ++reg)
                sMem[(g * 4 + reg) * 232 + d] = f2b(acc2[dt][reg]);
        }
    }

    // ---- epilogue: G[:,200:600] = [U_ | H*U_]; H re-read from global (L2-hot, f32)
    for (int r = 0; r < 16; ++r) {
        if (lane < 50) {
            int d0 = lane * 4;
            float* orow = Gout + (size_t)(n * 1024 + t0 + r) * 800;
            f32x4 h = *(const f32x4*)(Hbase + (size_t)r * 200 + d0);
            uint2 uraw = *(const uint2*)&sMem[r * 232 + d0];
            f32x4 u;
            u[0] = b2f((ushort)(uraw.x & 0xffffu)); u[1] = b2f((ushort)(uraw.x >> 16));
            u[2] = b2f((ushort)(uraw.y & 0xffffu)); u[3] = b2f((ushort)(uraw.y >> 16));
            f32x4 hu = h * u;
            __builtin_nontemporal_store(u,  (f32x4*)(orow + 200 + d0));
            __builtin_nontemporal_store(hu, (f32x4*)(orow + 400 + d0));
        }
    }
}

// ---------------- Kernel 2a: T-softmax stats -> a; zero Hbar ---------------------
__launch_bounds__(256)
__global__ void k2a_softmaxT(const float* __restrict__ cmg,
                             const float* __restrict__ SmaxWs,
                             float* __restrict__ aWs,
                             float* __restrict__ HbarWs) {
    __shared__ float red[8];
    const int tid = threadIdx.x, lane = tid & 63, wid = tid >> 6;
    const int n = blockIdx.x;

    float x[4], m[4];
    #pragma unroll
    for (int i = 0; i < 4; ++i) {
        int t = tid + 256 * i;
        float v = SmaxWs[n * 1024 + t];
        m[i] = cmg[(size_t)n * 1024 + t];
        x[i] = v * m[i];
    }
    float mx = fmaxf(fmaxf(x[0], x[1]), fmaxf(x[2], x[3]));
    #pragma unroll
    for (int off = 32; off >= 1; off >>= 1) mx = fmaxf(mx, __shfl_xor(mx, off));
    if (lane == 0) red[wid] = mx;
    __syncthreads();
    float M = fmaxf(fmaxf(red[0], red[1]), fmaxf(red[2], red[3]));
    __syncthreads();
    float e[4], z = 0.f, zm = 0.f;
    #pragma unroll
    for (int i = 0; i < 4; ++i) {
        e[i] = __expf(x[i] - M);
        z += e[i]; zm += e[i] * m[i];
    }
    #pragma unroll
    for (int off = 32; off >= 1; off >>= 1) {
        z  += __shfl_xor(z, off);
        zm += __shfl_xor(zm, off);
    }
    if (lane == 0) { red[wid] = z; red[4 + wid] = zm; }
    __syncthreads();
    float Z  = red[0] + red[1] + red[2] + red[3];
    float Zm = red[4] + red[5] + red[6] + red[7];
    float inv = 1.f / (Zm + 1e-13f * Z);
    #pragma unroll
    for (int i = 0; i < 4; ++i) aWs[n * 1024 + tid + 256 * i] = e[i] * m[i] * inv;
    if (tid < 200) HbarWs[n * 200 + tid] = 0.f;
}

// ---------------- Kernel 2b: Hbar += a-chunk @ H-chunk ---------------------------
__launch_bounds__(256)
__global__ void k2b_hbar(const float* __restrict__ Hg,
                         const float* __restrict__ aWs,
                         float* __restrict__ HbarWs) {
    __shared__ float sA[64];
    const int tid = threadIdx.x;
    const int n = blockIdx.y, t0 = blockIdx.x * 64;
    if (tid < 64) sA[tid] = aWs[n * 1024 + t0 + tid];
    __syncthreads();
    if (tid < 200) {
        const float* hp = Hg + (size_t)(n * 1024 + t0) * 200 + tid;
        float acc = 0.f;
        #pragma unroll 8
        for (int t = 0; t < 64; ++t) acc += sA[t] * hp[(size_t)t * 200];
        atomicAdd(HbarWs + n * 200 + tid, acc);
    }
}

// ---------------- Kernel 4: G[:,0:200] = H (exact); G[:,600:800] = H * Hbar ------
__launch_bounds__(256)
__global__ void k4_hh(const float* __restrict__ Hg,
                      const float* __restrict__ HbarWs,
                      float* __restrict__ Gout) {
    __shared__ __align__(16) float sHb[200];
    const int tid = threadIdx.x, lane = tid & 63, wid = tid >> 6;
    const int n = blockIdx.y, t0 = blockIdx.x * 64;
    if (tid < 200) sHb[tid] = HbarWs[n * 200 + tid];
    __syncthreads();
    for (int r = wid; r < 64; r += 4) {
        if (lane < 50) {
            int d0 = lane * 4;
            const float* hrow = Hg + (size_t)(n * 1024 + t0 + r) * 200;
            float* orow = Gout + (size_t)(n * 1024 + t0 + r) * 800;
            f32x4 h  = *(const f32x4*)(hrow + d0);
            f32x4 hb = *(const f32x4*)&sHb[d0];
            f32x4 hh = h * hb;
            __builtin_nontemporal_store(h,  (f32x4*)(orow + d0));
            __builtin_nontemporal_store(hh, (f32x4*)(orow + 600 + d0));
        }
    }
}

extern "C" void kernel_launch(void* const* d_in, const int* in_sizes, int n_in,
                              void* d_out, int out_size, void* d_ws, size_t ws_size,
                              hipStream_t stream) {
    (void)in_sizes; (void)n_in; (void)out_size; (void)ws_size;
    const float* Hg  = (const float*)d_in[0];
    const float* Ug  = (const float*)d_in[1];
    const float* cmg = (const float*)d_in[2];
    const float* qmg = (const float*)d_in[3];
    const float* wg  = (const float*)d_in[4];
    const float* bg  = (const float*)d_in[5];
    float* Gout = (float*)d_out;

    char* ws = (char*)d_ws;
    float*  SmaxWs = (float*) (ws);                    // 64*1024*4   =   262,144
    float*  aWs    = (float*) (ws + 262144);           // 64*1024*4   =   262,144
    float*  HbarWs = (float*) (ws + 524288);           // 64*200*4    =    51,200
    float*  cWs    = (float*) (ws + 575488);           // 64*64*4     =    16,384
    ushort* BfWs   = (ushort*)(ws + 591872);           // 64*28*512*2 = 1,835,008
    ushort* UfWs   = (ushort*)(ws + 2426880);          // 64*26*512*2 = 1,703,936
                                                       // total       = 4,130,816

    dim3 blk256(256, 1, 1);
    k0_prep<<<dim3(64, 1, 1), blk256, 0, stream>>>(Ug, wg, bg, BfWs, UfWs, cWs);
    k13_fused<<<dim3(64, 64, 1), dim3(64, 1, 1), 0, stream>>>(Hg, BfWs, cWs, qmg,
                                                              UfWs, SmaxWs, Gout);
    k2a_softmaxT<<<dim3(64, 1, 1), blk256, 0, stream>>>(cmg, SmaxWs, aWs, HbarWs);
    k2b_hbar<<<dim3(16, 64, 1), blk256, 0, stream>>>(Hg, aWs, HbarWs);
    k4_hh<<<dim3(16, 64, 1), blk256, 0, stream>>>(Hg, HbarWs, Gout);
}

// Round 8
// 309.347 us; speedup vs baseline: 1.2045x; 1.0297x over previous
//
#include <hip/hip_runtime.h>
#include <stdint.h>

#define NEGV -10000000.0f

typedef __attribute__((ext_vector_type(8))) short short8;
typedef __attribute__((ext_vector_type(4))) float f32x4;

__device__ __forceinline__ ushort f2b(float f) {
    uint32_t x = __float_as_uint(f);
    uint32_t r = x + 0x7FFFu + ((x >> 16) & 1u);
    return (ushort)(r >> 16);
}
__device__ __forceinline__ float b2f(ushort u) {
    union { float f; uint32_t i; } v; v.i = ((uint32_t)u) << 16; return v.f;
}

// ---------------- Kernel 0: per-n prep, outputs in MFMA FRAGMENT ORDER ----------
// Bf[n][kc*4+jt][lane][e] = bf16(Bhat[jt*16+li][kc*32+g*8+e]), lane=(g<<4)|li
// Uf[n][kc2*13+dt][lane][e] = bf16(U[kc2*32+g*8+e][dt*16+li])  (zero for d>=200)
// cW[n][j] = dot(U[j], w_u) + b
__launch_bounds__(256)
__global__ void k0_prep(const float* __restrict__ Ug, const float* __restrict__ wg,
                        const float* __restrict__ bg,
                        ushort* __restrict__ Bf, ushort* __restrict__ Uf,
                        float* __restrict__ cW) {
    __shared__ __align__(16) float sU[64][204];
    __shared__ float sW[600];
    const int tid = threadIdx.x, lane = tid & 63, wid = tid >> 6;
    const int n = blockIdx.x;

    for (int i = tid; i < 600; i += 256) sW[i] = wg[i];
    for (int r = wid; r < 64; r += 4) {
        const float* urow = Ug + (size_t)(n * 64 + r) * 200;
        if (lane < 50) *(float4*)&sU[r][lane * 4] = *(const float4*)(urow + lane * 4);
    }
    __syncthreads();
    const float bval = bg[0];

    // Bhat fragments: 28 chunks x 64 lanes x 8 bf16
    ushort* bfn = Bf + (size_t)n * (28 * 512);
    for (int item = tid; item < 28 * 64; item += 256) {
        int chunk = item >> 6, l2 = item & 63;
        int kc = chunk >> 2, jt = chunk & 3;
        int g2 = l2 >> 4, li2 = l2 & 15;
        int j = jt * 16 + li2;
        int d0 = kc * 32 + g2 * 8;
        short8 v;
        #pragma unroll
        for (int e = 0; e < 8; ++e) {
            int d = d0 + e;
            float bh = 0.f;
            if (d < 200) bh = sU[j][d] * sW[400 + d] + sW[d];
            v[e] = (short)f2b(bh);
        }
        *(short8*)(bfn + (size_t)item * 8) = v;
    }

    // U^T fragments: 26 chunks x 64 lanes x 8 bf16
    ushort* ufn = Uf + (size_t)n * (26 * 512);
    for (int item = tid; item < 26 * 64; item += 256) {
        int chunk = item >> 6, l2 = item & 63;
        int kc2 = chunk / 13, dt = chunk % 13;
        int g2 = l2 >> 4, li2 = l2 & 15;
        int d = dt * 16 + li2;
        int j0 = kc2 * 32 + g2 * 8;
        short8 v;
        #pragma unroll
        for (int e = 0; e < 8; ++e)
            v[e] = (d < 200) ? (short)f2b(sU[j0 + e][d]) : (short)0;
        *(short8*)(ufn + (size_t)item * 8) = v;
    }

    // c[j]
    for (int r = wid; r < 64; r += 4) {
        float part = 0.f;
        for (int d = lane; d < 200; d += 64) part += sU[r][d] * sW[200 + d];
        #pragma unroll
        for (int off = 32; off >= 1; off >>= 1) part += __shfl_xor(part, off);
        if (lane == 0) cW[n * 64 + r] = part + bval;
    }
}

// ---------------- Kernel A: GEMM1 + J-softmax -> Pf (fragment order), Smax -------
// 1 wave/block, 16 t-rows, LDS 9.75KB -> 16 blocks/CU.
__launch_bounds__(64, 4)
__global__ void kA_gemm1(const float* __restrict__ Hg,
                         const ushort* __restrict__ Bf,
                         const float* __restrict__ cW,
                         const float* __restrict__ qmg,
                         ushort* __restrict__ PfW,
                         float* __restrict__ SmaxWs) {
    __shared__ __align__(16) ushort sHb[16][232];  // H tile bf16
    __shared__ __align__(16) ushort sP[16][80];    // P tile bf16
    const int lane = threadIdx.x;
    const int g = lane >> 4, li = lane & 15;
    const int n = blockIdx.y, t0 = blockIdx.x * 16;

    // ---- stage H tile (coalesced float4) -> bf16 LDS ----
    const float* Hbase = Hg + (size_t)(n * 1024 + t0) * 200;
    #pragma unroll
    for (int it = 0; it < 13; ++it) {
        int idx = lane + it * 64;
        if (idx < 800) {
            int row = idx / 50, c4 = (idx - row * 50) * 4;
            float4 h = *(const float4*)(Hbase + (size_t)row * 200 + c4);
            uint2 wv;
            wv.x = ((uint)f2b(h.y) << 16) | (uint)f2b(h.x);
            wv.y = ((uint)f2b(h.w) << 16) | (uint)f2b(h.z);
            *(uint2*)&sHb[row][c4] = wv;
        }
    }
    #pragma unroll
    for (int it = 0; it < 4; ++it) {     // zero-pad cols 200..231
        int id2 = lane + it * 64;
        int row = id2 >> 4, c = id2 & 15;
        *(uint*)&sHb[row][200 + c * 2] = 0u;
    }

    // ---- GEMM1: A from LDS, B double-buffered coalesced loads ----
    const ushort* Bn = Bf + (size_t)n * (28 * 512);
    f32x4 acc[4];
    #pragma unroll
    for (int jt = 0; jt < 4; ++jt) acc[jt] = (f32x4){0.f, 0.f, 0.f, 0.f};
    const ushort* aRow = &sHb[li][g * 8];

    short8 bbuf[2][4];
    #pragma unroll
    for (int jt = 0; jt < 4; ++jt)
        bbuf[0][jt] = *(const short8*)(Bn + (size_t)((0 * 4 + jt) * 64 + lane) * 8);
    #pragma unroll
    for (int kc = 0; kc < 7; ++kc) {
        if (kc < 6) {
            #pragma unroll
            for (int jt = 0; jt < 4; ++jt)
                bbuf[(kc + 1) & 1][jt] =
                    *(const short8*)(Bn + (size_t)(((kc + 1) * 4 + jt) * 64 + lane) * 8);
        }
        short8 av = *(const short8*)(aRow + kc * 32);
        #pragma unroll
        for (int jt = 0; jt < 4; ++jt)
            acc[jt] = __builtin_amdgcn_mfma_f32_16x16x32_bf16(av, bbuf[kc & 1][jt],
                                                              acc[jt], 0, 0, 0);
    }

    // ---- J-softmax (identical math to verified kernel) ----
    float cj[4], qm[4];
    #pragma unroll
    for (int jt = 0; jt < 4; ++jt) {
        cj[jt] = cW[n * 64 + jt * 16 + li];
        qm[jt] = qmg[n * 64 + jt * 16 + li];
    }
    #pragma unroll
    for (int reg = 0; reg < 4; ++reg) {
        float x[4], y[4];
        float xm = -1e30f, ym = -1e30f;
        #pragma unroll
        for (int jt = 0; jt < 4; ++jt) {
            float s = acc[jt][reg] + cj[jt];
            x[jt] = s * qm[jt];
            y[jt] = (qm[jt] != 0.f) ? s : NEGV;
            xm = fmaxf(xm, x[jt]); ym = fmaxf(ym, y[jt]);
        }
        #pragma unroll
        for (int off = 1; off <= 8; off <<= 1) {
            xm = fmaxf(xm, __shfl_xor(xm, off));
            ym = fmaxf(ym, __shfl_xor(ym, off));
        }
        float e[4], z = 0.f, zm = 0.f;
        #pragma unroll
        for (int jt = 0; jt < 4; ++jt) {
            e[jt] = __expf(x[jt] - xm);
            z += e[jt]; zm += e[jt] * qm[jt];
        }
        #pragma unroll
        for (int off = 1; off <= 8; off <<= 1) {
            z  += __shfl_xor(z, off);
            zm += __shfl_xor(zm, off);
        }
        float inv = 1.f / (zm + 1e-13f * z);
        int trow = g * 4 + reg;
        #pragma unroll
        for (int jt = 0; jt < 4; ++jt) sP[trow][jt * 16 + li] = f2b(e[jt] * qm[jt] * inv);
        if (li == 0) SmaxWs[n * 1024 + t0 + trow] = ym;
    }

    // ---- store P in GEMM2 A-fragment order: Pf[tile][kc2*512 + lane*8 + e]
    //      = P[lane&15][kc2*32 + (lane>>4)*8 + e]  (coalesced 16B per lane) ----
    ushort* pf = PfW + (size_t)(n * 64 + blockIdx.x) * 1024;
    #pragma unroll
    for (int c2 = 0; c2 < 2; ++c2) {
        short8 v = *(const short8*)&sP[lane & 15][c2 * 32 + (lane >> 4) * 8];
        *(short8*)(pf + c2 * 512 + lane * 8) = v;
    }
}

// ---------------- Kernel 2a: T-softmax stats -> a; zero Hbar ---------------------
__launch_bounds__(256)
__global__ void k2a_softmaxT(const float* __restrict__ cmg,
                             const float* __restrict__ SmaxWs,
                             float* __restrict__ aWs,
                             float* __restrict__ HbarWs) {
    __shared__ float red[8];
    const int tid = threadIdx.x, lane = tid & 63, wid = tid >> 6;
    const int n = blockIdx.x;

    float x[4], m[4];
    #pragma unroll
    for (int i = 0; i < 4; ++i) {
        int t = tid + 256 * i;
        float v = SmaxWs[n * 1024 + t];
        m[i] = cmg[(size_t)n * 1024 + t];
        x[i] = v * m[i];
    }
    float mx = fmaxf(fmaxf(x[0], x[1]), fmaxf(x[2], x[3]));
    #pragma unroll
    for (int off = 32; off >= 1; off >>= 1) mx = fmaxf(mx, __shfl_xor(mx, off));
    if (lane == 0) red[wid] = mx;
    __syncthreads();
    float M = fmaxf(fmaxf(red[0], red[1]), fmaxf(red[2], red[3]));
    __syncthreads();
    float e[4], z = 0.f, zm = 0.f;
    #pragma unroll
    for (int i = 0; i < 4; ++i) {
        e[i] = __expf(x[i] - M);
        z += e[i]; zm += e[i] * m[i];
    }
    #pragma unroll
    for (int off = 32; off >= 1; off >>= 1) {
        z  += __shfl_xor(z, off);
        zm += __shfl_xor(zm, off);
    }
    if (lane == 0) { red[wid] = z; red[4 + wid] = zm; }
    __syncthreads();
    float Z  = red[0] + red[1] + red[2] + red[3];
    float Zm = red[4] + red[5] + red[6] + red[7];
    float inv = 1.f / (Zm + 1e-13f * Z);
    #pragma unroll
    for (int i = 0; i < 4; ++i) aWs[n * 1024 + tid + 256 * i] = e[i] * m[i] * inv;
    if (tid < 200) HbarWs[n * 200 + tid] = 0.f;
}

// ---------------- Kernel 2b: Hbar += a-chunk @ H-chunk ---------------------------
__launch_bounds__(256)
__global__ void k2b_hbar(const float* __restrict__ Hg,
                         const float* __restrict__ aWs,
                         float* __restrict__ HbarWs) {
    __shared__ float sA[64];
    const int tid = threadIdx.x;
    const int n = blockIdx.y, t0 = blockIdx.x * 64;
    if (tid < 64) sA[tid] = aWs[n * 1024 + t0 + tid];
    __syncthreads();
    if (tid < 200) {
        const float* hp = Hg + (size_t)(n * 1024 + t0) * 200 + tid;
        float acc = 0.f;
        #pragma unroll 8
        for (int t = 0; t < 64; ++t) acc += sA[t] * hp[(size_t)t * 200];
        atomicAdd(HbarWs + n * 200 + tid, acc);
    }
}

// ---------------- Kernel B: GEMM2 + ALL G writes in one pass ---------------------
// 256 thr (4 waves), 64-row tiles; wave-private U_ transpose (no __syncthreads);
// Hbar row-invariant -> 4 VGPRs; H read once; 4x f32x4 stores per row.
__launch_bounds__(256, 4)
__global__ void kB_gemm2_out(const float* __restrict__ Hg,
                             const ushort* __restrict__ Uf,
                             const ushort* __restrict__ PfW,
                             const float* __restrict__ HbarWs,
                             float* __restrict__ Gout) {
    __shared__ __align__(16) ushort sU2[64][208];   // 26,624 B
    const int tid = threadIdx.x, lane = tid & 63, w = tid >> 6;
    const int g = lane >> 4, li = lane & 15;
    const int n = blockIdx.y, r0 = blockIdx.x * 64;
    const int tIdx = blockIdx.x * 4 + w;

    // ---- GEMM2: both operands coalesced fragment loads ----
    const ushort* pf = PfW + (size_t)(n * 64 + tIdx) * 1024;
    const ushort* Un = Uf + (size_t)n * (26 * 512);
    f32x4 acc2[13];
    #pragma unroll
    for (int dt = 0; dt < 13; ++dt) acc2[dt] = (f32x4){0.f, 0.f, 0.f, 0.f};
    #pragma unroll
    for (int kc2 = 0; kc2 < 2; ++kc2) {
        short8 a2 = *(const short8*)(pf + kc2 * 512 + lane * 8);
        #pragma unroll
        for (int dt = 0; dt < 13; ++dt) {
            short8 bv = *(const short8*)(Un + (size_t)((kc2 * 13 + dt) * 64 + lane) * 8);
            acc2[dt] = __builtin_amdgcn_mfma_f32_16x16x32_bf16(a2, bv, acc2[dt], 0, 0, 0);
        }
    }

    // ---- wave-private transpose: C-layout -> row-major bf16 LDS ----
    #pragma unroll
    for (int dt = 0; dt < 13; ++dt) {
        int d = dt * 16 + li;
        if (d < 200) {
            #pragma unroll
            for (int reg = 0; reg < 4; ++reg)
                sU2[w * 16 + g * 4 + reg][d] = f2b(acc2[dt][reg]);
        }
    }

    // ---- Hbar is row-invariant: one f32x4 per lane ----
    const int d0 = lane * 4;
    f32x4 hbv = (f32x4){0.f, 0.f, 0.f, 0.f};
    if (lane < 50) hbv = *(const f32x4*)(HbarWs + n * 200 + d0);

    // ---- single-pass G: [H | U_ | H*U_ | H*Hbar], 800B coalesced segments ----
    for (int rr = 0; rr < 16; ++rr) {
        int r = w * 16 + rr;
        if (lane < 50) {
            const float* hrow = Hg + (size_t)(n * 1024 + r0 + r) * 200;
            float* orow = Gout + (size_t)(n * 1024 + r0 + r) * 800;
            f32x4 h = *(const f32x4*)(hrow + d0);
            uint2 uraw = *(const uint2*)&sU2[r][d0];
            f32x4 u;
            u[0] = b2f((ushort)(uraw.x & 0xffffu)); u[1] = b2f((ushort)(uraw.x >> 16));
            u[2] = b2f((ushort)(uraw.y & 0xffffu)); u[3] = b2f((ushort)(uraw.y >> 16));
            f32x4 hu = h * u;
            f32x4 hh = h * hbv;
            __builtin_nontemporal_store(h,  (f32x4*)(orow + d0));
            __builtin_nontemporal_store(u,  (f32x4*)(orow + 200 + d0));
            __builtin_nontemporal_store(hu, (f32x4*)(orow + 400 + d0));
            __builtin_nontemporal_store(hh, (f32x4*)(orow + 600 + d0));
        }
    }
}

extern "C" void kernel_launch(void* const* d_in, const int* in_sizes, int n_in,
                              void* d_out, int out_size, void* d_ws, size_t ws_size,
                              hipStream_t stream) {
    (void)in_sizes; (void)n_in; (void)out_size; (void)ws_size;
    const float* Hg  = (const float*)d_in[0];
    const float* Ug  = (const float*)d_in[1];
    const float* cmg = (const float*)d_in[2];
    const float* qmg = (const float*)d_in[3];
    const float* wg  = (const float*)d_in[4];
    const float* bg  = (const float*)d_in[5];
    float* Gout = (float*)d_out;

    char* ws = (char*)d_ws;
    float*  SmaxWs = (float*) (ws);                    // 64*1024*4   =   262,144
    float*  aWs    = (float*) (ws + 262144);           // 64*1024*4   =   262,144
    float*  HbarWs = (float*) (ws + 524288);           // 64*200*4    =    51,200
    float*  cWs    = (float*) (ws + 575488);           // 64*64*4     =    16,384
    ushort* BfWs   = (ushort*)(ws + 591872);           // 64*28*512*2 = 1,835,008
    ushort* UfWs   = (ushort*)(ws + 2426880);          // 64*26*512*2 = 1,703,936
    ushort* PfWs   = (ushort*)(ws + 4130816);          // 64*64*1024*2= 8,388,608
                                                       // total       = 12,519,424

    dim3 blk256(256, 1, 1);
    k0_prep<<<dim3(64, 1, 1), blk256, 0, stream>>>(Ug, wg, bg, BfWs, UfWs, cWs);
    kA_gemm1<<<dim3(64, 64, 1), dim3(64, 1, 1), 0, stream>>>(Hg, BfWs, cWs, qmg,
                                                             PfWs, SmaxWs);
    k2a_softmaxT<<<dim3(64, 1, 1), blk256, 0, stream>>>(cmg, SmaxWs, aWs, HbarWs);
    k2b_hbar<<<dim3(16, 64, 1), blk256, 0, stream>>>(Hg, aWs, HbarWs);
    kB_gemm2_out<<<dim3(16, 64, 1), blk256, 0, stream>>>(Hg, UfWs, PfWs, HbarWs, Gout);
}

// Round 9
// 306.061 us; speedup vs baseline: 1.2174x; 1.0107x over previous
//
#include <hip/hip_runtime.h>
#include <stdint.h>

#define NEGV -10000000.0f

typedef __attribute__((ext_vector_type(8))) short short8;
typedef __attribute__((ext_vector_type(4))) float f32x4;

__device__ __forceinline__ ushort f2b(float f) {
    uint32_t x = __float_as_uint(f);
    uint32_t r = x + 0x7FFFu + ((x >> 16) & 1u);
    return (ushort)(r >> 16);
}
__device__ __forceinline__ float b2f(ushort u) {
    union { float f; uint32_t i; } v; v.i = ((uint32_t)u) << 16; return v.f;
}

// ---------------- Kernel 0: per-n prep, outputs in MFMA FRAGMENT ORDER ----------
// Bf[n][kc*4+jt][lane][e] = bf16(Bhat[jt*16+li][kc*32+g*8+e]), lane=(g<<4)|li
// Uf[n][kc2*13+dt][lane][e] = bf16(U[kc2*32+g*8+e][dt*16+li])  (zero for d>=200)
// cW[n][j] = dot(U[j], w_u) + b
__launch_bounds__(256)
__global__ void k0_prep(const float* __restrict__ Ug, const float* __restrict__ wg,
                        const float* __restrict__ bg,
                        ushort* __restrict__ Bf, ushort* __restrict__ Uf,
                        float* __restrict__ cW) {
    __shared__ __align__(16) float sU[64][204];
    __shared__ float sW[600];
    const int tid = threadIdx.x, lane = tid & 63, wid = tid >> 6;
    const int n = blockIdx.x;

    for (int i = tid; i < 600; i += 256) sW[i] = wg[i];
    for (int r = wid; r < 64; r += 4) {
        const float* urow = Ug + (size_t)(n * 64 + r) * 200;
        if (lane < 50) *(float4*)&sU[r][lane * 4] = *(const float4*)(urow + lane * 4);
    }
    __syncthreads();
    const float bval = bg[0];

    // Bhat fragments: 28 chunks x 64 lanes x 8 bf16
    ushort* bfn = Bf + (size_t)n * (28 * 512);
    for (int item = tid; item < 28 * 64; item += 256) {
        int chunk = item >> 6, l2 = item & 63;
        int kc = chunk >> 2, jt = chunk & 3;
        int g2 = l2 >> 4, li2 = l2 & 15;
        int j = jt * 16 + li2;
        int d0 = kc * 32 + g2 * 8;
        short8 v;
        #pragma unroll
        for (int e = 0; e < 8; ++e) {
            int d = d0 + e;
            float bh = 0.f;
            if (d < 200) bh = sU[j][d] * sW[400 + d] + sW[d];
            v[e] = (short)f2b(bh);
        }
        *(short8*)(bfn + (size_t)item * 8) = v;
    }

    // U^T fragments: 26 chunks x 64 lanes x 8 bf16
    ushort* ufn = Uf + (size_t)n * (26 * 512);
    for (int item = tid; item < 26 * 64; item += 256) {
        int chunk = item >> 6, l2 = item & 63;
        int kc2 = chunk / 13, dt = chunk % 13;
        int g2 = l2 >> 4, li2 = l2 & 15;
        int d = dt * 16 + li2;
        int j0 = kc2 * 32 + g2 * 8;
        short8 v;
        #pragma unroll
        for (int e = 0; e < 8; ++e)
            v[e] = (d < 200) ? (short)f2b(sU[j0 + e][d]) : (short)0;
        *(short8*)(ufn + (size_t)item * 8) = v;
    }

    // c[j]
    for (int r = wid; r < 64; r += 4) {
        float part = 0.f;
        for (int d = lane; d < 200; d += 64) part += sU[r][d] * sW[200 + d];
        #pragma unroll
        for (int off = 32; off >= 1; off >>= 1) part += __shfl_xor(part, off);
        if (lane == 0) cW[n * 64 + r] = part + bval;
    }
}

// ---------------- Kernel A: GEMM1 + J-softmax + T-softmax PARTIALS ---------------
// 1 wave/block, 16 t-rows. Emits Pf (fragment order) and per-tile online-softmax
// partials (m_c, z_c, zm_c, v_c[d] = sum_t e^{x_t-m_c} cm_t H[t][d]).
__launch_bounds__(64, 4)
__global__ void kA_gemm1(const float* __restrict__ Hg,
                         const ushort* __restrict__ Bf,
                         const float* __restrict__ cW,
                         const float* __restrict__ qmg,
                         const float* __restrict__ cmg,
                         ushort* __restrict__ PfW,
                         ushort* __restrict__ vPart,
                         float* __restrict__ partM,
                         float* __restrict__ partZ,
                         float* __restrict__ partZm) {
    __shared__ __align__(16) ushort sHb[16][232];  // H tile bf16
    __shared__ __align__(16) ushort sP[16][80];    // P tile bf16
    __shared__ float sYm[16];                      // per-row masked max (Smax)
    __shared__ float sCm[16];                      // c_mask tile
    const int lane = threadIdx.x;
    const int g = lane >> 4, li = lane & 15;
    const int n = blockIdx.y, t0 = blockIdx.x * 16;

    // ---- stage H tile (coalesced float4) -> bf16 LDS ----
    const float* Hbase = Hg + (size_t)(n * 1024 + t0) * 200;
    #pragma unroll
    for (int it = 0; it < 13; ++it) {
        int idx = lane + it * 64;
        if (idx < 800) {
            int row = idx / 50, c4 = (idx - row * 50) * 4;
            float4 h = *(const float4*)(Hbase + (size_t)row * 200 + c4);
            uint2 wv;
            wv.x = ((uint)f2b(h.y) << 16) | (uint)f2b(h.x);
            wv.y = ((uint)f2b(h.w) << 16) | (uint)f2b(h.z);
            *(uint2*)&sHb[row][c4] = wv;
        }
    }
    #pragma unroll
    for (int it = 0; it < 4; ++it) {     // zero-pad cols 200..231
        int id2 = lane + it * 64;
        int row = id2 >> 4, c = id2 & 15;
        *(uint*)&sHb[row][200 + c * 2] = 0u;
    }
    if (lane < 16) sCm[lane] = cmg[(size_t)n * 1024 + t0 + lane];

    // ---- GEMM1: A from LDS, B double-buffered coalesced loads ----
    const ushort* Bn = Bf + (size_t)n * (28 * 512);
    f32x4 acc[4];
    #pragma unroll
    for (int jt = 0; jt < 4; ++jt) acc[jt] = (f32x4){0.f, 0.f, 0.f, 0.f};
    const ushort* aRow = &sHb[li][g * 8];

    short8 bbuf[2][4];
    #pragma unroll
    for (int jt = 0; jt < 4; ++jt)
        bbuf[0][jt] = *(const short8*)(Bn + (size_t)((0 * 4 + jt) * 64 + lane) * 8);
    #pragma unroll
    for (int kc = 0; kc < 7; ++kc) {
        if (kc < 6) {
            #pragma unroll
            for (int jt = 0; jt < 4; ++jt)
                bbuf[(kc + 1) & 1][jt] =
                    *(const short8*)(Bn + (size_t)(((kc + 1) * 4 + jt) * 64 + lane) * 8);
        }
        short8 av = *(const short8*)(aRow + kc * 32);
        #pragma unroll
        for (int jt = 0; jt < 4; ++jt)
            acc[jt] = __builtin_amdgcn_mfma_f32_16x16x32_bf16(av, bbuf[kc & 1][jt],
                                                              acc[jt], 0, 0, 0);
    }

    // ---- J-softmax (identical math to verified kernel) ----
    float cj[4], qm[4];
    #pragma unroll
    for (int jt = 0; jt < 4; ++jt) {
        cj[jt] = cW[n * 64 + jt * 16 + li];
        qm[jt] = qmg[n * 64 + jt * 16 + li];
    }
    #pragma unroll
    for (int reg = 0; reg < 4; ++reg) {
        float x[4], y[4];
        float xm = -1e30f, ym = -1e30f;
        #pragma unroll
        for (int jt = 0; jt < 4; ++jt) {
            float s = acc[jt][reg] + cj[jt];
            x[jt] = s * qm[jt];
            y[jt] = (qm[jt] != 0.f) ? s : NEGV;
            xm = fmaxf(xm, x[jt]); ym = fmaxf(ym, y[jt]);
        }
        #pragma unroll
        for (int off = 1; off <= 8; off <<= 1) {
            xm = fmaxf(xm, __shfl_xor(xm, off));
            ym = fmaxf(ym, __shfl_xor(ym, off));
        }
        float e[4], z = 0.f, zm = 0.f;
        #pragma unroll
        for (int jt = 0; jt < 4; ++jt) {
            e[jt] = __expf(x[jt] - xm);
            z += e[jt]; zm += e[jt] * qm[jt];
        }
        #pragma unroll
        for (int off = 1; off <= 8; off <<= 1) {
            z  += __shfl_xor(z, off);
            zm += __shfl_xor(zm, off);
        }
        float inv = 1.f / (zm + 1e-13f * z);
        int trow = g * 4 + reg;
        #pragma unroll
        for (int jt = 0; jt < 4; ++jt) sP[trow][jt * 16 + li] = f2b(e[jt] * qm[jt] * inv);
        if (li == 0) sYm[trow] = ym;
    }

    // ---- store P in GEMM2 A-fragment order (coalesced 16B per lane) ----
    ushort* pf = PfW + (size_t)(n * 64 + blockIdx.x) * 1024;
    #pragma unroll
    for (int c2 = 0; c2 < 2; ++c2) {
        short8 v = *(const short8*)&sP[lane & 15][c2 * 32 + (lane >> 4) * 8];
        *(short8*)(pf + c2 * 512 + lane * 8) = v;
    }

    // ---- T-softmax partials over this 16-row chunk (online-softmax algebra):
    //      x_t = Smax_t*cm_t; m_c=max; z=sum e; zm=sum e*cm; v[d]=sum e*cm*H[t][d]
    float m_c = -1e30f;
    #pragma unroll
    for (int t = 0; t < 16; ++t) m_c = fmaxf(m_c, sYm[t] * sCm[t]);
    float z = 0.f, zm = 0.f;
    f32x4 v = (f32x4){0.f, 0.f, 0.f, 0.f};
    const int d0 = (lane < 50) ? lane * 4 : 0;
    #pragma unroll
    for (int t = 0; t < 16; ++t) {
        float e = __expf(sYm[t] * sCm[t] - m_c);
        z += e;
        float wt = e * sCm[t];
        zm += wt;
        uint2 raw = *(const uint2*)&sHb[t][d0];
        v[0] += wt * b2f((ushort)(raw.x & 0xffffu));
        v[1] += wt * b2f((ushort)(raw.x >> 16));
        v[2] += wt * b2f((ushort)(raw.y & 0xffffu));
        v[3] += wt * b2f((ushort)(raw.y >> 16));
    }
    const int tile = n * 64 + blockIdx.x;
    if (lane < 50) {
        uint2 pv;
        pv.x = ((uint)f2b(v[1]) << 16) | (uint)f2b(v[0]);
        pv.y = ((uint)f2b(v[3]) << 16) | (uint)f2b(v[2]);
        *(uint2*)(vPart + (size_t)tile * 200 + lane * 4) = pv;
    }
    if (lane == 0) { partM[tile] = m_c; partZ[tile] = z; partZm[tile] = zm; }
}

// ---------------- Kernel C: combine 64 chunk-partials per n -> Hbar --------------
__launch_bounds__(256)
__global__ void kC_combine(const ushort* __restrict__ vPart,
                           const float* __restrict__ partM,
                           const float* __restrict__ partZ,
                           const float* __restrict__ partZm,
                           float* __restrict__ HbarWs) {
    __shared__ float sF[64];
    __shared__ float sInv;
    const int tid = threadIdx.x;
    const int n = blockIdx.x;

    if (tid < 64) {
        float mc  = partM[n * 64 + tid];
        float zc  = partZ[n * 64 + tid];
        float zmc = partZm[n * 64 + tid];
        float M = mc;
        #pragma unroll
        for (int off = 32; off >= 1; off >>= 1) M = fmaxf(M, __shfl_xor(M, off));
        float f = __expf(mc - M);
        sF[tid] = f;
        float Zc = zc * f, Zmc = zmc * f;
        #pragma unroll
        for (int off = 32; off >= 1; off >>= 1) {
            Zc  += __shfl_xor(Zc, off);
            Zmc += __shfl_xor(Zmc, off);
        }
        if (tid == 0) sInv = 1.f / (Zmc + 1e-13f * Zc);
    }
    __syncthreads();
    if (tid < 200) {
        float acc = 0.f;
        for (int c = 0; c < 64; ++c)
            acc += b2f(vPart[(size_t)(n * 64 + c) * 200 + tid]) * sF[c];
        HbarWs[n * 200 + tid] = acc * sInv;
    }
}

// ---------------- Kernel B: GEMM2 + ALL G writes in one pass ---------------------
__launch_bounds__(256, 4)
__global__ void kB_gemm2_out(const float* __restrict__ Hg,
                             const ushort* __restrict__ Uf,
                             const ushort* __restrict__ PfW,
                             const float* __restrict__ HbarWs,
                             float* __restrict__ Gout) {
    __shared__ __align__(16) ushort sU2[64][208];   // 26,624 B
    const int tid = threadIdx.x, lane = tid & 63, w = tid >> 6;
    const int g = lane >> 4, li = lane & 15;
    const int n = blockIdx.y, r0 = blockIdx.x * 64;
    const int tIdx = blockIdx.x * 4 + w;

    // ---- GEMM2: both operands coalesced fragment loads ----
    const ushort* pf = PfW + (size_t)(n * 64 + tIdx) * 1024;
    const ushort* Un = Uf + (size_t)n * (26 * 512);
    f32x4 acc2[13];
    #pragma unroll
    for (int dt = 0; dt < 13; ++dt) acc2[dt] = (f32x4){0.f, 0.f, 0.f, 0.f};
    #pragma unroll
    for (int kc2 = 0; kc2 < 2; ++kc2) {
        short8 a2 = *(const short8*)(pf + kc2 * 512 + lane * 8);
        #pragma unroll
        for (int dt = 0; dt < 13; ++dt) {
            short8 bv = *(const short8*)(Un + (size_t)((kc2 * 13 + dt) * 64 + lane) * 8);
            acc2[dt] = __builtin_amdgcn_mfma_f32_16x16x32_bf16(a2, bv, acc2[dt], 0, 0, 0);
        }
    }

    // ---- wave-private transpose: C-layout -> row-major bf16 LDS ----
    #pragma unroll
    for (int dt = 0; dt < 13; ++dt) {
        int d = dt * 16 + li;
        if (d < 200) {
            #pragma unroll
            for (int reg = 0; reg < 4; ++reg)
                sU2[w * 16 + g * 4 + reg][d] = f2b(acc2[dt][reg]);
        }
    }

    // ---- Hbar is row-invariant: one f32x4 per lane ----
    const int d0 = lane * 4;
    f32x4 hbv = (f32x4){0.f, 0.f, 0.f, 0.f};
    if (lane < 50) hbv = *(const f32x4*)(HbarWs + n * 200 + d0);

    // ---- single-pass G: [H | U_ | H*U_ | H*Hbar], 800B coalesced segments ----
    for (int rr = 0; rr < 16; ++rr) {
        int r = w * 16 + rr;
        if (lane < 50) {
            const float* hrow = Hg + (size_t)(n * 1024 + r0 + r) * 200;
            float* orow = Gout + (size_t)(n * 1024 + r0 + r) * 800;
            f32x4 h = *(const f32x4*)(hrow + d0);
            uint2 uraw = *(const uint2*)&sU2[r][d0];
            f32x4 u;
            u[0] = b2f((ushort)(uraw.x & 0xffffu)); u[1] = b2f((ushort)(uraw.x >> 16));
            u[2] = b2f((ushort)(uraw.y & 0xffffu)); u[3] = b2f((ushort)(uraw.y >> 16));
            f32x4 hu = h * u;
            f32x4 hh = h * hbv;
            __builtin_nontemporal_store(h,  (f32x4*)(orow + d0));
            __builtin_nontemporal_store(u,  (f32x4*)(orow + 200 + d0));
            __builtin_nontemporal_store(hu, (f32x4*)(orow + 400 + d0));
            __builtin_nontemporal_store(hh, (f32x4*)(orow + 600 + d0));
        }
    }
}

extern "C" void kernel_launch(void* const* d_in, const int* in_sizes, int n_in,
                              void* d_out, int out_size, void* d_ws, size_t ws_size,
                              hipStream_t stream) {
    (void)in_sizes; (void)n_in; (void)out_size; (void)ws_size;
    const float* Hg  = (const float*)d_in[0];
    const float* Ug  = (const float*)d_in[1];
    const float* cmg = (const float*)d_in[2];
    const float* qmg = (const float*)d_in[3];
    const float* wg  = (const float*)d_in[4];
    const float* bg  = (const float*)d_in[5];
    float* Gout = (float*)d_out;

    char* ws = (char*)d_ws;
    float*  HbarWs = (float*) (ws);                    // 64*200*4    =    51,200
    float*  cWs    = (float*) (ws + 51200);            // 64*64*4     =    16,384
    float*  partM  = (float*) (ws + 67584);            // 4096*4      =    16,384
    float*  partZ  = (float*) (ws + 83968);            // 4096*4      =    16,384
    float*  partZm = (float*) (ws + 100352);           // 4096*4      =    16,384
    ushort* vPart  = (ushort*)(ws + 116736);           // 4096*200*2  = 1,638,400
    ushort* BfWs   = (ushort*)(ws + 1755136);          // 64*28*512*2 = 1,835,008
    ushort* UfWs   = (ushort*)(ws + 3590144);          // 64*26*512*2 = 1,703,936
    ushort* PfWs   = (ushort*)(ws + 5294080);          // 64*64*1024*2= 8,388,608
                                                       // total       = 13,682,688

    dim3 blk256(256, 1, 1);
    k0_prep<<<dim3(64, 1, 1), blk256, 0, stream>>>(Ug, wg, bg, BfWs, UfWs, cWs);
    kA_gemm1<<<dim3(64, 64, 1), dim3(64, 1, 1), 0, stream>>>(Hg, BfWs, cWs, qmg, cmg,
                                                             PfWs, vPart, partM,
                                                             partZ, partZm);
    kC_combine<<<dim3(64, 1, 1), blk256, 0, stream>>>(vPart, partM, partZ, partZm,
                                                      HbarWs);
    kB_gemm2_out<<<dim3(16, 64, 1), blk256, 0, stream>>>(Hg, UfWs, PfWs, HbarWs, Gout);
}